// Round 5
// baseline (403.022 us; speedup 1.0000x reference)
//
#include <hip/hip_runtime.h>
#include <hip/hip_bf16.h>
#include <stdint.h>
#include <math.h>

#define DEV static __device__ __forceinline__

typedef short bf16x8 __attribute__((ext_vector_type(8)));
typedef float f32x4 __attribute__((ext_vector_type(4)));
typedef float f32x16 __attribute__((ext_vector_type(16)));
typedef unsigned short u16;

static constexpr int Sq   = 1024;
static constexpr int Dm   = 1024;
static constexpr int Hh   = 16;
static constexpr int Mrows = 4096; // B*S
static constexpr int DFFn = 4096;

// ---------- helpers ----------

DEV u16 f2bf(float f) {  // fp32 -> bf16 (RNE)
    union { float f; unsigned u; } c; c.f = f;
    unsigned u = c.u;
    return (u16)((u + 0x7FFFu + ((u >> 16) & 1u)) >> 16);
}

DEV unsigned cvt_pk_bf16(float lo, float hi) {  // D[15:0]=bf16(lo), D[31:16]=bf16(hi)
    unsigned r;
    asm("v_cvt_pk_bf16_f32 %0, %1, %2" : "=v"(r) : "v"(lo), "v"(hi));
    return r;
}

DEV void gload_lds16(void* lds, const void* g) {
    using gvp = __attribute__((address_space(1))) void*;
    using lvp = __attribute__((address_space(3))) void*;
    __builtin_amdgcn_global_load_lds((gvp)const_cast<void*>(g), (lvp)lds, 16, 0, 0);
}

// line-pair swizzle for [row][64B-row] LDS tiles: XOR byte bits 4-6 with line index
DEV int swz64(int L) { return L ^ (((L >> 7) & 7) << 4); }

// ---------- fp32 -> bf16 cast ----------

__global__ __launch_bounds__(256) void cast_bf16_kernel(
    const float* __restrict__ in, u16* __restrict__ out, int n4)
{
    int i = blockIdx.x * 256 + threadIdx.x;
    if (i >= n4) return;
    float4 v = ((const float4*)in)[i];
    ushort4 o;
    o.x = f2bf(v.x); o.y = f2bf(v.y); o.z = f2bf(v.z); o.w = f2bf(v.w);
    ((ushort4*)out)[i] = o;
}

// ---------- GEMM 256x256, BK=64, 8 waves, 8-phase counted-vmcnt pipeline ----------

template<int MODE>
__global__ __launch_bounds__(512) void gemm256_kernel(
    const u16* __restrict__ A, const u16* __restrict__ W,
    const float* __restrict__ bias, void* __restrict__ Cout,
    float* __restrict__ P1, float* __restrict__ P2, float* __restrict__ P3,
    int N, int ldK, int Kpass)
{
    __shared__ char ldsA[65536];
    __shared__ char ldsB[65536];
    const int tid = threadIdx.x;
    const int w = tid >> 6, l = tid & 63;
    const int lr = l & 15, lg = l >> 4;
    const int wr = w >> 2, wc = w & 3;
    const size_t tm = (size_t)blockIdx.y * 256;
    const size_t tn = (size_t)blockIdx.x * 256;
    const size_t kz = (size_t)blockIdx.z * Kpass;

    int offA[8], offB[4];
    #pragma unroll
    for (int m = 0; m < 8; ++m)
        offA[m] = swz64((wr * 128 + m * 16 + lr) * 64 + lg * 16);
    #pragma unroll
    for (int n = 0; n < 4; ++n)
        offB[n] = swz64((wc * 64 + n * 16 + lr) * 64 + lg * 16);

    const int Ls = swz64(tid * 16);
    const int sr = Ls >> 6, scc = Ls & 63;
    const size_t ldb = (size_t)ldK * 2;
    const char* aS = (const char*)A + (tm + sr) * ldb + kz * 2 + scc;
    const char* bS = (const char*)W + (tn + sr) * ldb + kz * 2 + scc;

    auto AH = [&](int b, int h) -> char* { return ldsA + (b * 2 + h) * 16384; };
    auto BH = [&](int b, int h) -> char* { return ldsB + (b * 2 + h) * 16384; };
    auto stage = [&](char* half, const char* src) {
        gload_lds16(half + w * 1024, src);
        gload_lds16(half + 8192 + w * 1024, src + 128 * ldb);
    };

    const int nt = Kpass >> 6;
    const int niter = nt >> 1;

    f32x4 acc[8][4] = {};
    bf16x8 bq[4];

    stage(AH(0, 0), aS);        stage(BH(0, 0), bS);
    stage(AH(0, 1), aS + 64);   stage(BH(0, 1), bS + 64);
    stage(AH(1, 0), aS + 128);  stage(BH(1, 0), bS + 128);
    asm volatile("s_waitcnt vmcnt(4)" ::: "memory");
    __builtin_amdgcn_s_barrier();

    for (int it = 0; it < niter; ++it) {
        const int t0 = it * 2;
        const bool last = (it == niter - 1);
        #pragma unroll
        for (int p = 0; p < 8; ++p) {
            const int ts = p >> 2;
            const int kk = (p >> 1) & 1, mh = p & 1;

            if (mh == 0) {
                #pragma unroll
                for (int n = 0; n < 4; ++n)
                    bq[n] = *(const bf16x8*)(BH(ts, kk) + offB[n]);
            }
            bf16x8 aF[4];
            #pragma unroll
            for (int q = 0; q < 4; ++q)
                aF[q] = *(const bf16x8*)(AH(ts, kk) + offA[mh * 4 + q]);

            if (p == 0)      { stage(AH(1, 1), aS + (size_t)(t0 + 1) * 128 + 64); }
            else if (p == 1) { stage(BH(1, 1), bS + (size_t)(t0 + 1) * 128 + 64); }
            else if (p == 2) { if (t0 + 2 < nt) stage(AH(0, 0), aS + (size_t)(t0 + 2) * 128); }
            else if (p == 3) { if (t0 + 2 < nt) stage(BH(0, 0), bS + (size_t)(t0 + 2) * 128); }
            else if (p == 4) { if (t0 + 2 < nt) stage(AH(0, 1), aS + (size_t)(t0 + 2) * 128 + 64); }
            else if (p == 5) { if (t0 + 2 < nt) stage(BH(0, 1), bS + (size_t)(t0 + 2) * 128 + 64); }
            else if (p == 6) { if (t0 + 3 < nt) stage(AH(1, 0), aS + (size_t)(t0 + 3) * 128); }
            else             { if (t0 + 3 < nt) stage(BH(1, 0), bS + (size_t)(t0 + 3) * 128); }

            if (p == 3) {
                if (last) asm volatile("s_waitcnt vmcnt(0)" ::: "memory");
                else      asm volatile("s_waitcnt vmcnt(4)" ::: "memory");
            } else if (p == 7 && !last) {
                asm volatile("s_waitcnt vmcnt(4)" ::: "memory");
            }
            __builtin_amdgcn_s_barrier();
            asm volatile("s_waitcnt lgkmcnt(0)");
            __builtin_amdgcn_sched_barrier(0);
            __builtin_amdgcn_s_setprio(1);
            #pragma unroll
            for (int q = 0; q < 4; ++q)
                #pragma unroll
                for (int n = 0; n < 4; ++n)
                    acc[mh * 4 + q][n] = __builtin_amdgcn_mfma_f32_16x16x32_bf16(
                        aF[q], bq[n], acc[mh * 4 + q][n], 0, 0, 0);
            __builtin_amdgcn_s_setprio(0);
            __builtin_amdgcn_s_barrier();
        }
    }

    float* Cp;
    if (MODE == 3) {
        Cp = (blockIdx.z == 0) ? (float*)Cout : (blockIdx.z == 1) ? P1 : (blockIdx.z == 2) ? P2 : P3;
    } else {
        Cp = (float*)Cout;
    }
    float bv[4];
    if (MODE != 3) {
        #pragma unroll
        for (int n = 0; n < 4; ++n) bv[n] = bias[tn + wc * 64 + n * 16 + lr];
    }
    #pragma unroll
    for (int m = 0; m < 8; ++m) {
        #pragma unroll
        for (int n = 0; n < 4; ++n) {
            const size_t col = tn + wc * 64 + n * 16 + lr;
            #pragma unroll
            for (int j = 0; j < 4; ++j) {
                const size_t row = tm + wr * 128 + m * 16 + lg * 4 + j;
                if (MODE == 3) {
                    Cp[row * (size_t)N + col] = acc[m][n][j];
                } else {
                    float v = acc[m][n][j] + bv[n];
                    if (MODE == 2) v = fmaxf(v, 0.f);
                    ((u16*)Cout)[row * (size_t)N + col] = f2bf(v);
                }
            }
        }
    }
}

// ---------- GEMM 64x128 (N=1024 shapes), swizzled LDS ----------

template<int OUT_BF16, int RELU>
__global__ __launch_bounds__(256) void gemm_bt64_kernel(
    const u16* __restrict__ A, const u16* __restrict__ W,
    const float* __restrict__ bias, void* __restrict__ Cout,
    int N, int K)
{
    __shared__ char Ald[64 * 64];
    __shared__ char Bld[128 * 64];
    const int tid = threadIdx.x;
    const int w  = tid >> 6, l = tid & 63;
    const int lr = l & 15,  lg = l >> 4;
    const size_t tm = (size_t)blockIdx.y * 64;
    const size_t tn = (size_t)blockIdx.x * 128;

    const int Ls = swz64(tid * 16);
    const int sr = Ls >> 6, scc = Ls & 63;
    const u16* Asrc = A + (tm + sr) * (size_t)K + (scc >> 1);
    const u16* Bsrc = W + (tn + sr) * (size_t)K + (scc >> 1);
    char* AldW = Ald + w * 1024;
    char* BldW = Bld + w * 1024;

    f32x4 acc[4][2] = {};

    for (int k0 = 0; k0 < K; k0 += 32) {
        __syncthreads();
        gload_lds16(AldW,        Asrc + k0);
        gload_lds16(BldW,        Bsrc + k0);
        gload_lds16(BldW + 4096, Bsrc + (size_t)64 * K + k0);
        __syncthreads();

        bf16x8 af[4], bfv[2];
        #pragma unroll
        for (int m = 0; m < 4; ++m)
            af[m] = *(const bf16x8*)(Ald + swz64((m * 16 + lr) * 64 + lg * 16));
        #pragma unroll
        for (int n = 0; n < 2; ++n)
            bfv[n] = *(const bf16x8*)(Bld + swz64((w * 32 + n * 16 + lr) * 64 + lg * 16));
        #pragma unroll
        for (int m = 0; m < 4; ++m)
            #pragma unroll
            for (int n = 0; n < 2; ++n)
                acc[m][n] = __builtin_amdgcn_mfma_f32_16x16x32_bf16(af[m], bfv[n], acc[m][n], 0, 0, 0);
    }

    float bv[2];
    #pragma unroll
    for (int n = 0; n < 2; ++n) bv[n] = bias[tn + w * 32 + n * 16 + lr];

    #pragma unroll
    for (int m = 0; m < 4; ++m) {
        #pragma unroll
        for (int n = 0; n < 2; ++n) {
            const size_t col = tn + w * 32 + n * 16 + lr;
            #pragma unroll
            for (int j = 0; j < 4; ++j) {
                const size_t row = tm + m * 16 + lg * 4 + j;
                float v = acc[m][n][j] + bv[n];
                if (RELU) v = fmaxf(v, 0.f);
                if (OUT_BF16) ((u16*)Cout)[row * (size_t)N + col] = f2bf(v);
                else          ((float*)Cout)[row * (size_t)N + col] = v;
            }
        }
    }
}

// ---------- flash attention: 32x32 swapped QK^T, in-lane softmax ----------
// grid: (S/128, B*H); 4 waves; wave w owns q-rows qw0=q0+w*32..+31 (q = lane&31).
// QK^T = mfma_32x32x16(K, Q): lane holds s[n][r] = score(key = kv0+n*32+crow(r,hi),
// q = qw0+(lane&31)), crow(r,hi) = (r&3)+8*(r>>2)+4*hi, hi = lane>>5. Lane covers
// 32 of 64 keys; partner lane^32 the rest -> softmax = in-lane tree + 1 shfl_xor(32).
// P -> PV A-frag: 16 cvt_pk words + 16 shfl_xor(32) + cndmask assembly:
// frag(ks)[t] = word m=(t&1)+4(ks&1)+2hi owned by half (t>>1). PV: o[dn] += pa[ks]*V^T.

template<int CAUSAL>
__global__ __launch_bounds__(256) void attn_kernel(
    const u16* __restrict__ Qm, int ldq,
    const u16* __restrict__ Km, int ldk,
    const u16* __restrict__ Vm, int ldv,
    u16* __restrict__ Om)
{
    __shared__ u16 Kld[2][64 * 64];
    __shared__ u16 Vt [2][64 * 64];

    const int tid = threadIdx.x;
    const int w = tid >> 6, l = tid & 63;
    const int lq = l & 31;          // q-index / d-col / key-row depending on role
    const int hi = l >> 5;
    const int bh = blockIdx.y;
    const int b = bh >> 4, h = bh & 15;
    const int q0 = blockIdx.x * 128;
    const int qw0 = q0 + w * 32;
    const size_t baseQ = (size_t)b * Sq * ldq + (size_t)h * 64;
    const size_t baseK = (size_t)b * Sq * ldk + (size_t)h * 64;
    const size_t baseV = (size_t)b * Sq * ldv + (size_t)h * 64;
    const size_t baseO = (size_t)b * Sq * Dm  + (size_t)h * 64;

    // Q fragments (B-operand: col=lane&31 -> q, k=(lane>>5)*8+i per 16-k step)
    const int qrow = qw0 + lq;
    bf16x8 bq[4];
    #pragma unroll
    for (int kc = 0; kc < 4; ++kc)
        bq[kc] = *(const bf16x8*)&Qm[baseQ + (size_t)qrow * ldq + kc * 16 + hi * 8];

    const int kr  = tid >> 2;
    const int kcB = (tid & 3) * 32;
    const int vdg = tid >> 5;
    const int vkp = tid & 31;

    f32x16 o0 = {}, o1 = {};
    float mj = -INFINITY;    // running max, raw-score units, q = lq
    float lj = 0.f;

    const int kv_end = CAUSAL ? (q0 + 128) : Sq;
    const int nt = kv_end >> 6;
    const float cexp = 0.125f * 1.44269504f;   // 1/sqrt(64) * log2(e)

    uint4 ka, kb, va, vb;
    auto loadKV = [&](int kv) {
        ka = *(const uint4*)&Km[baseK + (size_t)(kv + kr) * ldk + kcB / 2];
        kb = *(const uint4*)&Km[baseK + (size_t)(kv + kr) * ldk + kcB / 2 + 8];
        va = *(const uint4*)&Vm[baseV + (size_t)(kv + vkp * 2    ) * ldv + vdg * 8];
        vb = *(const uint4*)&Vm[baseV + (size_t)(kv + vkp * 2 + 1) * ldv + vdg * 8];
    };

    loadKV(0);

    for (int t = 0; t < nt; ++t) {
        const int bsel = t & 1;
        const int kv0 = t << 6;
        {   // stage regs -> LDS (swizzled)
            char* Kb_ = (char*)Kld[bsel];
            char* Vb_ = (char*)Vt[bsel];
            const int sk = (kr & 7) << 4;
            *(uint4*)(Kb_ + kr * 128 + ((kcB     ) ^ sk)) = ka;
            *(uint4*)(Kb_ + kr * 128 + ((kcB + 16) ^ sk)) = kb;
            const u16* pa_ = (const u16*)&va;
            const u16* pb_ = (const u16*)&vb;
            #pragma unroll
            for (int i = 0; i < 8; ++i) {
                const int d = vdg * 8 + i;
                unsigned val = (unsigned)pa_[i] | ((unsigned)pb_[i] << 16);
                *(unsigned*)(Vb_ + d * 128 + ((vkp * 4) ^ ((d & 7) << 4))) = val;
            }
        }
        __syncthreads();
        if (t + 1 < nt) loadKV((t + 1) << 6);

        if (!CAUSAL || kv0 <= qw0 + 31) {
            const char* Kb_ = (const char*)Kld[bsel];
            const char* Vb_ = (const char*)Vt[bsel];
            const int skq = (lq & 7) << 4;

            // QK^T swapped: sv[n] = K_sub(n) x Q, 32x32x16 over dk=64
            f32x16 sv[2] = {};
            #pragma unroll
            for (int n = 0; n < 2; ++n) {
                const int rowb = (n * 32 + lq) * 128;
                #pragma unroll
                for (int kc = 0; kc < 4; ++kc) {
                    bf16x8 kf = *(const bf16x8*)(Kb_ + rowb + ((kc * 32 + hi * 16) ^ skq));
                    sv[n] = __builtin_amdgcn_mfma_f32_32x32x16_bf16(kf, bq[kc], sv[n], 0, 0, 0);
                }
            }

            // mask (diag tiles only) + in-lane max
            const bool diag = CAUSAL && (kv0 + 63 > qw0);
            float tmax = -INFINITY;
            #pragma unroll
            for (int n = 0; n < 2; ++n)
                #pragma unroll
                for (int r = 0; r < 16; ++r) {
                    float v = sv[n][r];
                    if (diag) {
                        int key = kv0 + n * 32 + (r & 3) + 8 * (r >> 2) + 4 * hi;
                        if (key > qrow) v = -3.0e8f;
                    }
                    sv[n][r] = v;
                    tmax = fmaxf(tmax, v);
                }
            tmax = fmaxf(tmax, __shfl_xor(tmax, 32));

            const bool noresc = __all(tmax <= mj);
            const float nm = noresc ? mj : fmaxf(mj, tmax);
            const float nmc = nm * cexp;

            // exp (scale folded into fma) + in-lane sum
            float rs0 = 0.f, rs1 = 0.f;
            #pragma unroll
            for (int n = 0; n < 2; ++n)
                #pragma unroll
                for (int r = 0; r < 16; ++r) {
                    float e = exp2f(fmaf(sv[n][r], cexp, -nmc));
                    sv[n][r] = e;
                    if (r & 1) rs1 += e; else rs0 += e;
                }
            float rs = rs0 + rs1;
            rs += __shfl_xor(rs, 32);

            if (noresc) {
                lj += rs;
            } else {
                const float scl = exp2f((mj - nm) * cexp);
                lj = lj * scl + rs;
                mj = nm;
                #pragma unroll
                for (int r = 0; r < 16; ++r) {
                    float sr = __shfl(scl, (r & 3) + 8 * (r >> 2) + 4 * hi);
                    o0[r] *= sr; o1[r] *= sr;
                }
            }

            // pack P -> bf16 words; exchange halves
            unsigned wv[2][8], rv[2][8];
            #pragma unroll
            for (int n = 0; n < 2; ++n)
                #pragma unroll
                for (int m = 0; m < 8; ++m)
                    wv[n][m] = cvt_pk_bf16(sv[n][2 * m], sv[n][2 * m + 1]);
            #pragma unroll
            for (int n = 0; n < 2; ++n)
                #pragma unroll
                for (int m = 0; m < 8; ++m)
                    rv[n][m] = (unsigned)__shfl_xor((int)wv[n][m], 32);

            // PV: 4 k-slots of 16 keys; A-frag assembled per derivation above
            #pragma unroll
            for (int ks = 0; ks < 4; ++ks) {
                const int n = ks >> 1, q_ = (ks & 1) * 4;
                union { unsigned u[4]; bf16x8 v; } pa;
                pa.u[0] = hi ? rv[n][q_ + 2] : wv[n][q_ + 0];
                pa.u[1] = hi ? rv[n][q_ + 3] : wv[n][q_ + 1];
                pa.u[2] = hi ? wv[n][q_ + 2] : rv[n][q_ + 0];
                pa.u[3] = hi ? wv[n][q_ + 3] : rv[n][q_ + 1];
                const int koff = (ks * 32 + hi * 16);
                bf16x8 vf0 = *(const bf16x8*)(Vb_ + lq * 128        + (koff ^ skq));
                bf16x8 vf1 = *(const bf16x8*)(Vb_ + (32 + lq) * 128 + (koff ^ skq));
                o0 = __builtin_amdgcn_mfma_f32_32x32x16_bf16(pa.v, vf0, o0, 0, 0, 0);
                o1 = __builtin_amdgcn_mfma_f32_32x32x16_bf16(pa.v, vf1, o1, 0, 0, 0);
            }
        }
        __syncthreads();
    }

    // output: row = qw0 + crow(r,hi), col = dn*32 + lq
    const float linv = 1.0f / lj;
    #pragma unroll
    for (int r = 0; r < 16; ++r) {
        const int crow = (r & 3) + 8 * (r >> 2) + 4 * hi;
        const float lr_ = __shfl(linv, crow);
        const size_t rowoff = baseO + (size_t)(qw0 + crow) * Dm;
        Om[rowoff + lq]      = f2bf(o0[r] * lr_);
        Om[rowoff + 32 + lq] = f2bf(o1[r] * lr_);
    }
}

// ---------- add + LayerNorm ----------

__global__ __launch_bounds__(256) void add_ln_kernel(
    const float* __restrict__ A, const float* __restrict__ Bv,
    const float* __restrict__ g, const float* __restrict__ be,
    float* __restrict__ Y, u16* __restrict__ Ybf)
{
    const int row = blockIdx.x;
    const int tid = threadIdx.x;
    const size_t off = (size_t)row * Dm;
    float4 a4 = ((const float4*)(A + off))[tid];
    float4 b4 = ((const float4*)(Bv + off))[tid];
    float4 xv;
    xv.x = a4.x + b4.x; xv.y = a4.y + b4.y; xv.z = a4.z + b4.z; xv.w = a4.w + b4.w;
    float s = xv.x + xv.y + xv.z + xv.w;
    float q = xv.x * xv.x + xv.y * xv.y + xv.z * xv.z + xv.w * xv.w;
    #pragma unroll
    for (int m = 1; m < 64; m <<= 1) {
        s += __shfl_xor(s, m);
        q += __shfl_xor(q, m);
    }
    __shared__ float ss[4], qq[4];
    if ((tid & 63) == 0) { ss[tid >> 6] = s; qq[tid >> 6] = q; }
    __syncthreads();
    s = ss[0] + ss[1] + ss[2] + ss[3];
    q = qq[0] + qq[1] + qq[2] + qq[3];
    const float mean = s * (1.f / 1024.f);
    const float var  = q * (1.f / 1024.f) - mean * mean;
    const float rstd = rsqrtf(var + 1e-5f);
    float4 g4  = ((const float4*)g)[tid];
    float4 be4 = ((const float4*)be)[tid];
    float4 y;
    y.x = (xv.x - mean) * rstd * g4.x + be4.x;
    y.y = (xv.y - mean) * rstd * g4.y + be4.y;
    y.z = (xv.z - mean) * rstd * g4.z + be4.z;
    y.w = (xv.w - mean) * rstd * g4.w + be4.w;
    ((float4*)(Y + off))[tid] = y;
    if (Ybf) {
        ushort4 ob;
        ob.x = f2bf(y.x); ob.y = f2bf(y.y); ob.z = f2bf(y.z); ob.w = f2bf(y.w);
        ((ushort4*)(Ybf + off))[tid] = ob;
    }
}

// ---------- 4-partial reduce + bias + add + LayerNorm (ff2 epilogue) ----------

__global__ __launch_bounds__(256) void add_ln_red4_kernel(
    const float* __restrict__ X,
    const float* __restrict__ P0, const float* __restrict__ P1,
    const float* __restrict__ P2, const float* __restrict__ P3,
    const float* __restrict__ bias,
    const float* __restrict__ g, const float* __restrict__ be,
    float* __restrict__ Y)
{
    const int row = blockIdx.x;
    const int tid = threadIdx.x;
    const size_t off = (size_t)row * Dm;
    float4 a4 = ((const float4*)(X + off))[tid];
    float4 q0 = ((const float4*)(P0 + off))[tid];
    float4 q1 = ((const float4*)(P1 + off))[tid];
    float4 q2 = ((const float4*)(P2 + off))[tid];
    float4 q3 = ((const float4*)(P3 + off))[tid];
    float4 b4 = ((const float4*)bias)[tid];
    float4 xv;
    xv.x = a4.x + q0.x + q1.x + q2.x + q3.x + b4.x;
    xv.y = a4.y + q0.y + q1.y + q2.y + q3.y + b4.y;
    xv.z = a4.z + q0.z + q1.z + q2.z + q3.z + b4.z;
    xv.w = a4.w + q0.w + q1.w + q2.w + q3.w + b4.w;
    float s = xv.x + xv.y + xv.z + xv.w;
    float q = xv.x * xv.x + xv.y * xv.y + xv.z * xv.z + xv.w * xv.w;
    #pragma unroll
    for (int m = 1; m < 64; m <<= 1) {
        s += __shfl_xor(s, m);
        q += __shfl_xor(q, m);
    }
    __shared__ float ss[4], qq[4];
    if ((tid & 63) == 0) { ss[tid >> 6] = s; qq[tid >> 6] = q; }
    __syncthreads();
    s = ss[0] + ss[1] + ss[2] + ss[3];
    q = qq[0] + qq[1] + qq[2] + qq[3];
    const float mean = s * (1.f / 1024.f);
    const float var  = q * (1.f / 1024.f) - mean * mean;
    const float rstd = rsqrtf(var + 1e-5f);
    float4 g4  = ((const float4*)g)[tid];
    float4 be4 = ((const float4*)be)[tid];
    float4 y;
    y.x = (xv.x - mean) * rstd * g4.x + be4.x;
    y.y = (xv.y - mean) * rstd * g4.y + be4.y;
    y.z = (xv.z - mean) * rstd * g4.z + be4.z;
    y.w = (xv.w - mean) * rstd * g4.w + be4.w;
    ((float4*)(Y + off))[tid] = y;
}

// ---------- launch ----------

extern "C" void kernel_launch(void* const* d_in, const int* in_sizes, int n_in,
                              void* d_out, int out_size, void* d_ws, size_t ws_size,
                              hipStream_t stream)
{
    const float* x       = (const float*)d_in[0];
    const float* enc     = (const float*)d_in[1];
    const float* sa_wq   = (const float*)d_in[4];
    const float* sa_bq   = (const float*)d_in[5];
    const float* sa_wk   = (const float*)d_in[6];
    const float* sa_bk   = (const float*)d_in[7];
    const float* sa_wv   = (const float*)d_in[8];
    const float* sa_bv   = (const float*)d_in[9];
    const float* sa_wo   = (const float*)d_in[10];
    const float* sa_bo   = (const float*)d_in[11];
    const float* ca_in_w = (const float*)d_in[12];
    const float* ca_in_b = (const float*)d_in[13];
    const float* ca_out_w= (const float*)d_in[14];
    const float* ca_out_b= (const float*)d_in[15];
    const float* ff_w1   = (const float*)d_in[16];
    const float* ff_b1   = (const float*)d_in[17];
    const float* ff_w2   = (const float*)d_in[18];
    const float* ff_b2   = (const float*)d_in[19];
    const float* n1_g = (const float*)d_in[20];
    const float* n1_b = (const float*)d_in[21];
    const float* n2_g = (const float*)d_in[22];
    const float* n2_b = (const float*)d_in[23];
    const float* n3_g = (const float*)d_in[24];
    const float* n3_b = (const float*)d_in[25];

    char* p = (char*)d_ws;
    auto take = [&](size_t bytes) -> char* {
        char* r = p; p += (bytes + 255) & ~(size_t)255; return r;
    };
    const size_t MDbf = (size_t)Mrows * Dm * 2;
    const size_t MDf  = (size_t)Mrows * Dm * 4;
    const size_t DD   = (size_t)Dm * Dm;

    u16* xb     = (u16*)take(MDbf);
    u16* encb   = (u16*)take(MDbf);
    u16* wqkv   = (u16*)take(3 * DD * 2);
    u16* wob    = (u16*)take(DD * 2);
    u16* cainb  = (u16*)take(3 * DD * 2);
    u16* caoutb = (u16*)take(DD * 2);
    u16* fw1b   = (u16*)take((size_t)DFFn * Dm * 2);
    u16* fw2b   = (u16*)take((size_t)Dm * DFFn * 2);
    float* bias3= (float*)take(3 * Dm * 4);
    u16* SCR    = (u16*)take((size_t)Mrows * DFFn * 2);
    u16* AOb    = (u16*)take(MDbf);
    float* tmpf = (float*)take(MDf);
    float* x1f  = (float*)take(MDf);
    u16*   x1b  = (u16*)take(MDbf);
    float* x2f  = (float*)take(MDf);
    u16*   x2b  = (u16*)take(MDbf);
    if ((size_t)(p - (char*)d_ws) > ws_size) return;

    float* fp0 = (float*)AOb;
    float* fp1 = (float*)((char*)AOb + MDf);
    float* fp2 = (float*)((char*)AOb + 2 * MDf);
    float* fp3 = (float*)xb;

    auto cast = [&](const float* src, u16* dst, size_t n) {
        int n4 = (int)(n / 4);
        cast_bf16_kernel<<<dim3((n4 + 255) / 256), dim3(256), 0, stream>>>(src, dst, n4);
    };
    cast(x, xb, (size_t)Mrows * Dm);
    cast(enc, encb, (size_t)Mrows * Dm);
    cast(sa_wq, wqkv,          DD);
    cast(sa_wk, wqkv + DD,     DD);
    cast(sa_wv, wqkv + 2 * DD, DD);
    cast(sa_wo, wob, DD);
    cast(ca_in_w, cainb, 3 * DD);
    cast(ca_out_w, caoutb, DD);
    cast(ff_w1, fw1b, (size_t)DFFn * Dm);
    cast(ff_w2, fw2b, (size_t)Dm * DFFn);
    hipMemcpyAsync(bias3,          sa_bq, Dm * 4, hipMemcpyDeviceToDevice, stream);
    hipMemcpyAsync(bias3 + Dm,     sa_bk, Dm * 4, hipMemcpyDeviceToDevice, stream);
    hipMemcpyAsync(bias3 + 2 * Dm, sa_bv, Dm * 4, hipMemcpyDeviceToDevice, stream);

    const dim3 blk(256);
    const dim3 blk512(512);
    const size_t M4 = (size_t)Mrows * Dm;

    // ---- self-attention block ----
    gemm256_kernel<1><<<dim3(12, 16), blk512, 0, stream>>>(
        xb, wqkv, bias3, (void*)SCR, nullptr, nullptr, nullptr, 3072, Dm, Dm);
    attn_kernel<1><<<dim3(Sq / 128, 4 * Hh), blk, 0, stream>>>(SCR, 3072, SCR + 1024, 3072, SCR + 2048, 3072, AOb);
    gemm_bt64_kernel<0, 0><<<dim3(Dm / 128, Mrows / 64), blk, 0, stream>>>(AOb, wob, sa_bo, (void*)tmpf, Dm, Dm);
    add_ln_kernel<<<dim3(Mrows), blk, 0, stream>>>(x, tmpf, n1_g, n1_b, x1f, x1b);

    // ---- cross-attention block ----
    u16* Qc  = SCR;
    u16* KVc = SCR + M4;
    gemm_bt64_kernel<1, 0><<<dim3(Dm / 128, Mrows / 64), blk, 0, stream>>>(x1b, cainb, ca_in_b, (void*)Qc, Dm, Dm);
    gemm256_kernel<1><<<dim3(8, 16), blk512, 0, stream>>>(
        encb, cainb + DD, ca_in_b + Dm, (void*)KVc, nullptr, nullptr, nullptr, 2048, Dm, Dm);
    attn_kernel<0><<<dim3(Sq / 128, 4 * Hh), blk, 0, stream>>>(Qc, 1024, KVc, 2048, KVc + 1024, 2048, AOb);
    gemm_bt64_kernel<0, 0><<<dim3(Dm / 128, Mrows / 64), blk, 0, stream>>>(AOb, caoutb, ca_out_b, (void*)tmpf, Dm, Dm);
    add_ln_kernel<<<dim3(Mrows), blk, 0, stream>>>(x1f, tmpf, n2_g, n2_b, x2f, x2b);

    // ---- feed-forward block ----
    u16* ffh = SCR;
    gemm256_kernel<2><<<dim3(16, 16), blk512, 0, stream>>>(
        x2b, fw1b, ff_b1, (void*)ffh, nullptr, nullptr, nullptr, DFFn, Dm, Dm);
    gemm256_kernel<3><<<dim3(4, 16, 4), blk512, 0, stream>>>(
        ffh, fw2b, nullptr, (void*)fp0, fp1, fp2, fp3, Dm, DFFn, 1024);
    add_ln_red4_kernel<<<dim3(Mrows), blk, 0, stream>>>(x2f, fp0, fp1, fp2, fp3, ff_b2, n3_g, n3_b, (float*)d_out);
}